// Round 8
// baseline (56.090 us; speedup 1.0000x reference)
//
#include <hip/hip_runtime.h>
#include <stdint.h>

typedef unsigned short u16;

#define B_ 8
#define C_ 64
#define H_ 128
#define W_ 128
#define OC_ 64
#define HO_ 128
#define WO_ 128
#define HWC_ (H_*W_*C_)   // elems per batch in NHWC
#define PADW 72           // padded clds row (f16): 144B, 16B-aligned

typedef __attribute__((ext_vector_type(8))) _Float16 f16x8;
typedef __attribute__((ext_vector_type(2))) _Float16 h2;
typedef __attribute__((ext_vector_type(4))) float f32x4;

__device__ __forceinline__ u16 f2h(float f) {
  union { _Float16 h; u16 u; } c; c.h = (_Float16)f; return c.u;
}
__device__ __forceinline__ uint32_t pkh2(float f) {   // (h,h) packed pair
  union { _Float16 h[2]; uint32_t u; } c;
  const _Float16 h = (_Float16)f;
  c.h[0] = h; c.h[1] = h; return c.u;
}

// ---- prep 1: weight [OC][C][3][3] f32 -> wk2 in MFMA A-fragment order (f16) ----
// wk2 flat index = (((k*2 + wr)*2 + m)*2 + kk)*512 + lane*8 + j
//   oc = wr*32 + m*16 + (lane&15);  c = kk*32 + (lane>>4)*8 + j
__global__ void wprep_kernel(const float* __restrict__ w, u16* __restrict__ wk2) {
  const int idx = blockIdx.x * 256 + threadIdx.x;   // 144*256 = 36864 exact
  const int j    = idx & 7;
  const int lane = (idx >> 3) & 63;
  const int kk   = (idx >> 9) & 1;
  const int m    = (idx >> 10) & 1;
  const int wr   = (idx >> 11) & 1;
  const int k    = idx >> 12;
  const int oc = wr*32 + m*16 + (lane & 15);
  const int c  = kk*32 + (lane >> 4)*8 + j;
  wk2[idx] = f2h(w[(oc*C_ + c)*9 + k]);
}

// ---- prep 2: input NCHW f32 -> NHWC f16 ----
__global__ __launch_bounds__(256) void nhwc_kernel(const float* __restrict__ in,
                                                   u16* __restrict__ nhwc) {
  __shared__ float t[64][65];
  const int b = blockIdx.z, h = blockIdx.y, w0 = blockIdx.x * 64;
  const int tid = threadIdx.x;
  for (int idx = tid; idx < 64*64; idx += 256) {
    int c = idx >> 6, w = idx & 63;
    t[w][c] = in[((b*C_ + c)*H_ + h)*W_ + w0 + w];
  }
  __syncthreads();
  for (int idx = tid; idx < 64*64; idx += 256) {
    int w = idx >> 6, c = idx & 63;
    nhwc[((b*H_ + h)*W_ + w0 + w)*C_ + c] = f2h(t[w][c]);
  }
}

// packed-f16 bilinear blend: 2 channels per call, 4 v_pk_fma_f16
__device__ __forceinline__ uint32_t blendh(uint32_t g00, uint32_t g01,
                                           uint32_t g10, uint32_t g11, uint4 w) {
  h2 s = __builtin_bit_cast(h2, g00) * __builtin_bit_cast(h2, w.x)
       + __builtin_bit_cast(h2, g01) * __builtin_bit_cast(h2, w.y)
       + __builtin_bit_cast(h2, g10) * __builtin_bit_cast(h2, w.z)
       + __builtin_bit_cast(h2, g11) * __builtin_bit_cast(h2, w.w);
  return __builtin_bit_cast(uint32_t, s);
}

// pinned 16B global load: asm volatile cannot be sunk by the scheduler,
// and the compiler inserts NO waitcnt for it (we count by hand).
#define GLOAD4(dst, p) \
  asm volatile("global_load_dwordx4 %0, %1, off" : "=v"(dst) : "v"(p))

// hand-counted wait + full scheduling fence (rule #18)
#define WAITV(n) { \
    asm volatile("s_waitcnt vmcnt(" #n ")" ::: "memory"); \
    __builtin_amdgcn_sched_barrier(0); }

// raw region barrier: ds_writes visible, VMEM loads STAY IN FLIGHT
#define RBAR() { \
    asm volatile("s_waitcnt lgkmcnt(0)" ::: "memory"); \
    __builtin_amdgcn_sched_barrier(0); \
    __builtin_amdgcn_s_barrier(); \
    __builtin_amdgcn_sched_barrier(0); }

// ---- main: 64px strip x 64oc per block, 4 waves, f16 MFMA,
//      asm-pinned VMEM pipeline, counted vmcnt, raw barriers ----
__global__ __launch_bounds__(256, 3) void mdconv_main(
    const float* __restrict__ offs, const float* __restrict__ mask,
    const float* __restrict__ bias, const u16* __restrict__ nhwc,
    const u16* __restrict__ wk2, float* __restrict__ out)
{
  __shared__ u16 clds[2][64*PADW];  // 18432 B, double-buffered
  __shared__ int2 pA[576];          //  4608 B  {base, dx|dy<<16}
  __shared__ uint4 pW[576];         //  9216 B  corner weights, packed (h,h) f16x2

  const int tid = threadIdx.x;
  const int lane = tid & 63;
  const int wv = tid >> 6;
  const int b = blockIdx.z;
  const int p = blockIdx.y;
  const int q0 = blockIdx.x * 64;

  // phase 1: per-(k,px) sampling params -> LDS
  for (int item = tid; item < 576; item += 256) {
    const int k = item >> 6;
    const int px = item & 63;
    const int q = q0 + px;
    const int ky = k / 3, kx = k % 3;
    const float oy = offs[((b*18 + 2*k)*HO_ + p)*WO_ + q];
    const float ox = offs[((b*18 + 2*k + 1)*HO_ + p)*WO_ + q];
    const float mm = mask[((b*9 + k)*HO_ + p)*WO_ + q];
    const float py  = (float)(ky + p - 1) + oy;
    const float pxx = (float)(kx + q - 1) + ox;
    const float y0f = floorf(py), x0f = floorf(pxx);
    const int y0 = (int)y0f, x0 = (int)x0f;
    const int y1 = y0 + 1, x1 = x0 + 1;
    const float wy1 = py - y0f, wx1 = pxx - x0f;
    const float wy0 = 1.f - wy1, wx0 = 1.f - wx1;
    const bool vy0 = (y0 >= 0) & (y0 < H_);
    const bool vy1 = (y1 >= 0) & (y1 < H_);
    const bool vx0 = (x0 >= 0) & (x0 < W_);
    const bool vx1 = (x1 >= 0) & (x1 < W_);
    const float w00 = (vy0 & vx0) ? wy0*wx0*mm : 0.f;
    const float w01 = (vy0 & vx1) ? wy0*wx1*mm : 0.f;
    const float w10 = (vy1 & vx0) ? wy1*wx0*mm : 0.f;
    const float w11 = (vy1 & vx1) ? wy1*wx1*mm : 0.f;
    const int y0c = min(max(y0,0),H_-1), y1c = min(max(y1,0),H_-1);
    const int x0c = min(max(x0,0),W_-1), x1c = min(max(x1,0),W_-1);
    // invalid corners have zero weight, so clamped deltas are always safe
    const int dx = (x1c - x0c) * C_;        // 0 or 64
    const int dy = (y1c - y0c) * W_ * C_;   // 0 or 8192
    pA[item] = make_int2(b*HWC_ + (y0c*W_ + x0c)*C_, dx | (dy << 16));
    pW[item] = make_uint4(pkh2(w00), pkh2(w01), pkh2(w10), pkh2(w11));
  }
  __syncthreads();

  f32x4 acc00 = {0.f,0.f,0.f,0.f};
  f32x4 acc01 = acc00, acc10 = acc00, acc11 = acc00;
  const int wr = wv >> 1, wc = wv & 1;
  const int px0 = tid >> 3;          // 0..31 (second item: +32)
  const int c8 = (tid & 7) * 8;      // channel chunk start

  uint4 g0[8], g1[8];                // ping-pong gather regs (parity = k&1)
  uint4 a0[4], a1[4];                // ping-pong A-fragment regs (parity = k&1)

#define ISSUE_G(kk_, gbuf) { \
    const int piA = (kk_)*64 + px0, piB = piA + 32; \
    const int2 aA = pA[piA]; const int2 aB = pA[piB]; \
    const u16* sA = nhwc + aA.x + c8; \
    const u16* sB = nhwc + aB.x + c8; \
    const int dxA = aA.y & 0xFFFF, dyA = ((uint32_t)aA.y) >> 16; \
    const int dxB = aB.y & 0xFFFF, dyB = ((uint32_t)aB.y) >> 16; \
    GLOAD4(gbuf[0], (const uint4*)(sA)); \
    GLOAD4(gbuf[1], (const uint4*)(sA + dxA)); \
    GLOAD4(gbuf[2], (const uint4*)(sA + dyA)); \
    GLOAD4(gbuf[3], (const uint4*)(sA + dyA + dxA)); \
    GLOAD4(gbuf[4], (const uint4*)(sB)); \
    GLOAD4(gbuf[5], (const uint4*)(sB + dxB)); \
    GLOAD4(gbuf[6], (const uint4*)(sB + dyB)); \
    GLOAD4(gbuf[7], (const uint4*)(sB + dyB + dxB)); }

#define ISSUE_A(kk_, abuf) { \
    const u16* wg = wk2 + ((kk_)*2 + wr)*2048 + lane*8; \
    GLOAD4(abuf[0], (const uint4*)(wg)); \
    GLOAD4(abuf[1], (const uint4*)(wg + 512)); \
    GLOAD4(abuf[2], (const uint4*)(wg + 1024)); \
    GLOAD4(abuf[3], (const uint4*)(wg + 1536)); }

#define BLEND_WR(kk_, gbuf) { \
    const int piA = (kk_)*64 + px0, piB = piA + 32; \
    const uint4 wA = pW[piA]; const uint4 wB = pW[piB]; \
    uint4 rA, rB; \
    rA.x = blendh(gbuf[0].x, gbuf[1].x, gbuf[2].x, gbuf[3].x, wA); \
    rA.y = blendh(gbuf[0].y, gbuf[1].y, gbuf[2].y, gbuf[3].y, wA); \
    rA.z = blendh(gbuf[0].z, gbuf[1].z, gbuf[2].z, gbuf[3].z, wA); \
    rA.w = blendh(gbuf[0].w, gbuf[1].w, gbuf[2].w, gbuf[3].w, wA); \
    rB.x = blendh(gbuf[4].x, gbuf[5].x, gbuf[6].x, gbuf[7].x, wB); \
    rB.y = blendh(gbuf[4].y, gbuf[5].y, gbuf[6].y, gbuf[7].y, wB); \
    rB.z = blendh(gbuf[4].z, gbuf[5].z, gbuf[6].z, gbuf[7].z, wB); \
    rB.w = blendh(gbuf[4].w, gbuf[5].w, gbuf[6].w, gbuf[7].w, wB); \
    *(uint4*)(&clds[(kk_)&1][px0*PADW + c8]) = rA; \
    *(uint4*)(&clds[(kk_)&1][(px0+32)*PADW + c8]) = rB; }

// region k: issue G(k+2), A(k+1); wait vmcnt(WN) => A(k),G(k+1) landed,
// this region's issues stay in flight across the raw barrier.
#define REGION(k_, GCUR, GNXT, ACUR, ANXT, ISSG, ISSA, WN) { \
    const u16* cb = &clds[(k_)&1][(wc*32 + (lane & 15))*PADW + (lane >> 4)*8]; \
    const f16x8 b00 = *(const f16x8*)(cb); \
    const f16x8 b01 = *(const f16x8*)(cb + 32); \
    const f16x8 b10 = *(const f16x8*)(cb + 16*PADW); \
    const f16x8 b11 = *(const f16x8*)(cb + 16*PADW + 32); \
    if (ISSG) { ISSUE_G((k_)+2, GCUR); } \
    if (ISSA) { ISSUE_A((k_)+1, ANXT); } \
    WAITV(WN); \
    acc00 = __builtin_amdgcn_mfma_f32_16x16x32_f16(__builtin_bit_cast(f16x8, ACUR[0]), b00, acc00, 0, 0, 0); \
    acc00 = __builtin_amdgcn_mfma_f32_16x16x32_f16(__builtin_bit_cast(f16x8, ACUR[1]), b01, acc00, 0, 0, 0); \
    acc01 = __builtin_amdgcn_mfma_f32_16x16x32_f16(__builtin_bit_cast(f16x8, ACUR[0]), b10, acc01, 0, 0, 0); \
    acc01 = __builtin_amdgcn_mfma_f32_16x16x32_f16(__builtin_bit_cast(f16x8, ACUR[1]), b11, acc01, 0, 0, 0); \
    acc10 = __builtin_amdgcn_mfma_f32_16x16x32_f16(__builtin_bit_cast(f16x8, ACUR[2]), b00, acc10, 0, 0, 0); \
    acc10 = __builtin_amdgcn_mfma_f32_16x16x32_f16(__builtin_bit_cast(f16x8, ACUR[3]), b01, acc10, 0, 0, 0); \
    acc11 = __builtin_amdgcn_mfma_f32_16x16x32_f16(__builtin_bit_cast(f16x8, ACUR[2]), b10, acc11, 0, 0, 0); \
    acc11 = __builtin_amdgcn_mfma_f32_16x16x32_f16(__builtin_bit_cast(f16x8, ACUR[3]), b11, acc11, 0, 0, 0); \
    if ((k_) < 8) { BLEND_WR((k_)+1, GNXT); RBAR(); } }

  // prologue: fill the pipe
  ISSUE_G(0, g0);
  ISSUE_G(1, g1);
  ISSUE_A(0, a0);
  WAITV(12);          // G(0) landed; G(1)+A(0) = 12 still in flight
  BLEND_WR(0, g0);
  RBAR();

  //       k  GCUR GNXT ACUR ANXT  G  A  vmcnt
  REGION(  0,  g0,  g1,  a0,  a1,  1, 1, 12);
  REGION(  1,  g1,  g0,  a1,  a0,  1, 1, 12);
  REGION(  2,  g0,  g1,  a0,  a1,  1, 1, 12);
  REGION(  3,  g1,  g0,  a1,  a0,  1, 1, 12);
  REGION(  4,  g0,  g1,  a0,  a1,  1, 1, 12);
  REGION(  5,  g1,  g0,  a1,  a0,  1, 1, 12);
  REGION(  6,  g0,  g1,  a0,  a1,  1, 1, 12);
  REGION(  7,  g1,  g0,  a1,  a0,  0, 1,  4);
  REGION(  8,  g0,  g1,  a0,  a1,  0, 0,  0);

  // epilogue: C/D layout col=lane&15 (px), row=(lane>>4)*4+j (oc)
  const int qc = q0 + wc*32 + (lane & 15);
  const int ocr = wr*32 + (lane >> 4)*4;
  #pragma unroll
  for (int m = 0; m < 2; ++m) {
    #pragma unroll
    for (int n = 0; n < 2; ++n) {
      const f32x4 a = (m==0) ? (n==0 ? acc00 : acc01) : (n==0 ? acc10 : acc11);
      #pragma unroll
      for (int j = 0; j < 4; ++j) {
        const int oc = ocr + m*16 + j;
        out[((b*OC_ + oc)*HO_ + p)*WO_ + qc + n*16] = a[j] + bias[oc];
      }
    }
  }
}

extern "C" void kernel_launch(void* const* d_in, const int* in_sizes, int n_in,
                              void* d_out, int out_size, void* d_ws, size_t ws_size,
                              hipStream_t stream) {
  const float* input  = (const float*)d_in[0];
  const float* offset = (const float*)d_in[1];
  const float* mask   = (const float*)d_in[2];
  const float* weight = (const float*)d_in[3];
  const float* bias   = (const float*)d_in[4];
  float* out = (float*)d_out;

  u16* nhwc = (u16*)d_ws;                              // 16 MB
  u16* wk2  = nhwc + (size_t)B_*H_*W_*C_;              // 72 KB

  hipLaunchKernelGGL(wprep_kernel, dim3(144), dim3(256), 0, stream, weight, wk2);
  hipLaunchKernelGGL(nhwc_kernel, dim3(2, 128, 8), dim3(256), 0, stream, input, nhwc);
  hipLaunchKernelGGL(mdconv_main, dim3(2, 128, 8), dim3(256), 0, stream,
                     offset, mask, bias, nhwc, wk2, out);
}